// Round 6
// baseline (2348.798 us; speedup 1.0000x reference)
//
#include <hip/hip_runtime.h>

#define BG 8
#define NP 4096
#define MC 2048
#define KN 64

// Exact-rounding squared distance matching JAX/np f32 semantics:
// ((dx*dx + dy*dy) + dz*dz), no FMA contraction.
__device__ __forceinline__ float dist2(float ax, float ay, float az,
                                       float bx, float by, float bz) {
    float dx = __fsub_rn(ax, bx), dy = __fsub_rn(ay, by), dz = __fsub_rn(az, bz);
    return __fadd_rn(__fadd_rn(__fmul_rn(dx, dx), __fmul_rn(dy, dy)), __fmul_rn(dz, dz));
}

// f32 max reduce step via DPP (VALU-speed cross-lane). bound_ctrl=1 -> OOB
// lanes contribute 0, safe since operands are >= 0 (or -1 sentinel beaten by 0).
template <int CTRL>
__device__ __forceinline__ float dppmax(float v) {
    int t = __builtin_amdgcn_update_dpp(0, __float_as_int(v), CTRL, 0xf, 0xf, true);
    return fmaxf(v, __int_as_float(t));
}

// ---- Kernel 1: FPS (blocks 0..7, 8 waves x 8 pts/thread) + y = x@W1x + b1 (blocks 8..263) ----
__global__ __launch_bounds__(512) void k1_fps_y(
    const float* __restrict__ pos, const float* __restrict__ x,
    const float* __restrict__ w1, const float* __restrict__ b1,
    float* __restrict__ y,
    float* __restrict__ out_pos, float* __restrict__ out_batch)
{
    __shared__ float smem[12480];
    const int tid = threadIdx.x;
    if (blockIdx.x < BG) {
        const int b = blockIdx.x;
        const float* pg = pos + (size_t)b * NP * 3;
        for (int i = tid; i < NP * 3; i += 512) smem[i] = pg[i];
        __syncthreads();
        const int lane = tid & 63, wq = tid >> 6;   // 8 waves
        float px[8], py[8], pz[8], mind[8];
        const int base = tid * 8;
        #pragma unroll
        for (int i = 0; i < 8; i++) {
            px[i] = smem[(base + i) * 3];
            py[i] = smem[(base + i) * 3 + 1];
            pz[i] = smem[(base + i) * 3 + 2];
            mind[i] = 1e30f;
        }
        float4* slotA = (float4*)(smem + 12288);    // [2][8] : (V, x, y, z) double-buffered
        float cx = smem[0], cy = smem[1], cz = smem[2];
        // per-thread result buffer: this thread owns centers m = tid*4 + s
        float rx0, ry0, rz0, rx1, ry1, rz1, rx2, ry2, rz2, rx3, ry3, rz3;
        rx0 = cx; ry0 = cy; rz0 = cz;   // m=0 (owned by tid 0; harmless elsewhere, overwritten)
        rx1 = ry1 = rz1 = 0.f; rx2 = ry2 = rz2 = 0.f; rx3 = ry3 = rz3 = 0.f;
        for (int m = 1; m < MC; m++) {
            // update min distances; track thread-local (max, first idx)
            float bv = -1.0f; int bi = base;
            #pragma unroll
            for (int i = 0; i < 8; i++) {
                float d = dist2(px[i], py[i], pz[i], cx, cy, cz);
                float nm = fminf(mind[i], d);
                mind[i] = nm;
                if (nm > bv) { bv = nm; bi = base + i; }  // strict > keeps first idx
            }
            // speculative fetch of own candidate's position (overlaps DPP chain)
            float wx = smem[bi * 3], wy = smem[bi * 3 + 1], wz = smem[bi * 3 + 2];
            // wave max via DPP
            float v = bv;
            v = dppmax<0x111>(v);  // row_shr:1
            v = dppmax<0x112>(v);  // row_shr:2
            v = dppmax<0x114>(v);  // row_shr:4
            v = dppmax<0x118>(v);  // row_shr:8
            v = dppmax<0x142>(v);  // row_bcast:15
            v = dppmax<0x143>(v);  // row_bcast:31
            const float V = __int_as_float(__builtin_amdgcn_readlane(__float_as_int(v), 63));
            // first candidate lane = min index (lane order == index order within wave)
            unsigned long long mk = __ballot(bv == V);
            const int db = (m & 1) * 8;
            if (lane == (int)(__ffsll((long long)mk) - 1))
                slotA[db + wq] = make_float4(V, wx, wy, wz);
            __syncthreads();
            // 8-slot tournament (strict > , ascending wave => first-index semantics)
            const float4* qa = slotA + db;
            float4 q0 = qa[0], q1 = qa[1], q2 = qa[2], q3 = qa[3];
            float4 q4 = qa[4], q5 = qa[5], q6 = qa[6], q7 = qa[7];
            float4 a0 = (q1.x > q0.x) ? q1 : q0;
            float4 a1 = (q3.x > q2.x) ? q3 : q2;
            float4 a2 = (q5.x > q4.x) ? q5 : q4;
            float4 a3 = (q7.x > q6.x) ? q7 : q6;
            float4 b0 = (a1.x > a0.x) ? a1 : a0;
            float4 b1 = (a3.x > a2.x) ? a3 : a2;
            float4 w  = (b1.x > b0.x) ? b1 : b0;
            cx = w.y; cy = w.z; cz = w.w;
            // buffer result in the owning thread's registers (no global traffic in-loop)
            if ((m >> 2) == tid) {
                const int s = m & 3;
                if      (s == 0) { rx0 = cx; ry0 = cy; rz0 = cz; }
                else if (s == 1) { rx1 = cx; ry1 = cy; rz1 = cz; }
                else if (s == 2) { rx2 = cx; ry2 = cy; rz2 = cz; }
                else             { rx3 = cx; ry3 = cy; rz3 = cz; }
            }
        }
        // write out this thread's 4 centers
        const int c0 = b * MC + tid * 4;
        out_pos[(size_t)c0 * 3 + 0]  = rx0; out_pos[(size_t)c0 * 3 + 1]  = ry0; out_pos[(size_t)c0 * 3 + 2]  = rz0;
        out_pos[(size_t)c0 * 3 + 3]  = rx1; out_pos[(size_t)c0 * 3 + 4]  = ry1; out_pos[(size_t)c0 * 3 + 5]  = rz1;
        out_pos[(size_t)c0 * 3 + 6]  = rx2; out_pos[(size_t)c0 * 3 + 7]  = ry2; out_pos[(size_t)c0 * 3 + 8]  = rz2;
        out_pos[(size_t)c0 * 3 + 9]  = rx3; out_pos[(size_t)c0 * 3 + 10] = ry3; out_pos[(size_t)c0 * 3 + 11] = rz3;
        out_batch[c0 + 0] = (float)b; out_batch[c0 + 1] = (float)b;
        out_batch[c0 + 2] = (float)b; out_batch[c0 + 3] = (float)b;
    } else {
        // -------- y = x @ W1x + b1 (128 points per block) --------
        const int q = blockIdx.x - BG;   // 0..255
        const int p0 = q * 128;
        float* xs = smem;                 // 128 x 65 (padded)
        float* wsm = smem + 8320;         // 64 x 64
        float* bsm = smem + 12416;        // 64
        for (int i = tid; i < 8192; i += 512)
            xs[(i >> 6) * 65 + (i & 63)] = x[(size_t)p0 * 64 + i];
        for (int i = tid; i < 4096; i += 512) wsm[i] = w1[i];
        if (tid < 64) bsm[tid] = b1[tid];
        __syncthreads();
        const int pl = tid >> 2, oq = tid & 3;
        float acc[16];
        #pragma unroll
        for (int u = 0; u < 16; u++) acc[u] = bsm[oq * 16 + u];
        for (int f = 0; f < 64; f++) {
            float xv = xs[pl * 65 + f];
            const float4* wp = (const float4*)&wsm[f * 64 + oq * 16];
            float4 a = wp[0], b4 = wp[1], c4 = wp[2], d4 = wp[3];
            acc[0] = fmaf(xv, a.x, acc[0]);   acc[1] = fmaf(xv, a.y, acc[1]);
            acc[2] = fmaf(xv, a.z, acc[2]);   acc[3] = fmaf(xv, a.w, acc[3]);
            acc[4] = fmaf(xv, b4.x, acc[4]);  acc[5] = fmaf(xv, b4.y, acc[5]);
            acc[6] = fmaf(xv, b4.z, acc[6]);  acc[7] = fmaf(xv, b4.w, acc[7]);
            acc[8] = fmaf(xv, c4.x, acc[8]);  acc[9] = fmaf(xv, c4.y, acc[9]);
            acc[10] = fmaf(xv, c4.z, acc[10]); acc[11] = fmaf(xv, c4.w, acc[11]);
            acc[12] = fmaf(xv, d4.x, acc[12]); acc[13] = fmaf(xv, d4.y, acc[13]);
            acc[14] = fmaf(xv, d4.z, acc[14]); acc[15] = fmaf(xv, d4.w, acc[15]);
        }
        float4* yo = (float4*)&y[((size_t)p0 + pl) * 64 + oq * 16];
        yo[0] = make_float4(acc[0], acc[1], acc[2], acc[3]);
        yo[1] = make_float4(acc[4], acc[5], acc[6], acc[7]);
        yo[2] = make_float4(acc[8], acc[9], acc[10], acc[11]);
        yo[3] = make_float4(acc[12], acc[13], acc[14], acc[15]);
    }
}

// ---------------- Kernel 2: radius-capped kNN per center (centers from out_pos) -------------
__global__ __launch_bounds__(256) void k2_nbr(
    const float* __restrict__ pos, const float* __restrict__ out_pos,
    int* __restrict__ nbr, int* __restrict__ cntg)
{
    __shared__ float smem[12288 + 4 * 480 * 2];
    const int tid = threadIdx.x, lane = tid & 63, wv = tid >> 6;
    const int b = blockIdx.x >> 5, blk = blockIdx.x & 31;
    const float* pg = pos + (size_t)b * NP * 3;
    for (int i = tid; i < NP * 3; i += 256) smem[i] = pg[i];
    __syncthreads();
    float2* cb = (float2*)(smem + 12288) + wv * 480;
    const int wi = blk * 4 + wv;    // 0..127
    for (int t = 0; t < 16; t++) {
        const int m = wi + 128 * t, ci = b * MC + m;
        const float cx = out_pos[(size_t)ci * 3], cy = out_pos[(size_t)ci * 3 + 1], cz = out_pos[(size_t)ci * 3 + 2];
        int cnt = 0;
        for (int c = 0; c < 64; c++) {
            const int p = c * 64 + lane;
            float d2 = dist2(smem[p * 3], smem[p * 3 + 1], smem[p * 3 + 2], cx, cy, cz);
            bool inr = d2 <= 0.25f;
            unsigned long long mk = __ballot(inr);
            int pre = __popcll(mk & ((1ull << lane) - 1ull));
            int wp = cnt + pre;
            if (inr && wp < 480) cb[wp] = make_float2(d2, __int_as_float(p));
            cnt += __popcll(mk);
        }
        if (cnt > 480) cnt = 480;
        if (cnt <= KN) {
            if (lane < cnt) { float2 e = cb[lane]; nbr[(size_t)ci * KN + lane] = __float_as_int(e.y); }
            if (lane == 0) cntg[ci] = cnt;
        } else {
            for (int basej = 0; basej < cnt; basej += 64) {
                int jj = basej + lane;
                float dj = 3.4e38f; int ij = 0x7fffffff;
                bool act = jj < cnt;
                if (act) { float2 e = cb[jj]; dj = e.x; ij = __float_as_int(e.y); }
                int rank = 0;
                for (int l = 0; l < cnt; l++) {
                    float2 e = cb[l];
                    float dl = e.x; int il = __float_as_int(e.y);
                    if (dl < dj || (dl == dj && il < ij)) rank++;
                }
                if (act && rank < KN) nbr[(size_t)ci * KN + rank] = ij;
            }
            if (lane == 0) cntg[ci] = KN;
        }
    }
}

// ------- Kernel 3: per-center MLP + masked max (1 center/wave, prefetch pipeline) -------
__global__ __launch_bounds__(256, 2) void k3_mlp(
    const float* __restrict__ y, const float* __restrict__ pos,
    const int* __restrict__ nbr, const int* __restrict__ cntg,
    const float* __restrict__ w1, const float* __restrict__ w2, const float* __restrict__ b2,
    const float* __restrict__ w3, const float* __restrict__ b3,
    const float* __restrict__ out_pos, float* __restrict__ out_x)
{
    __shared__ float smem[4 * 136];
    const int tid = threadIdx.x, o = tid & 63, wv = tid >> 6;
    float w2c[64], w3a[64], w3b[64];
    #pragma unroll
    for (int f = 0; f < 64; f++) {
        w2c[f] = w2[f * 64 + o];
        w3a[f] = w3[f * 128 + o];
        w3b[f] = w3[f * 128 + 64 + o];
    }
    const float b2v = b2[o], b3av = b3[o], b3bv = b3[o + 64];
    const float wp0 = w1[64 * 64 + o], wp1 = w1[65 * 64 + o], wp2 = w1[66 * 64 + o];
    float* st1 = smem + wv * 136;
    float* st2 = st1 + 68;
    const int ci = blockIdx.x * 4 + wv;   // 0..16383
    const int b = ci >> 11;               // / MC
    const int kc = cntg[ci];
    const float cx = out_pos[(size_t)ci * 3], cy = out_pos[(size_t)ci * 3 + 1], cz = out_pos[(size_t)ci * 3 + 2];
    {
        const int j0 = nbr[(size_t)ci * KN];
        const size_t pj0 = (size_t)b * NP + j0;
        float yv = y[pj0 * 64 + o];
        float jx = pos[pj0 * 3], jy = pos[pj0 * 3 + 1], jz = pos[pj0 * 3 + 2];
        float mA = -3.4e38f, mB = -3.4e38f;
        for (int k = 0; k < kc; k++) {
            const int kn = (k + 1 < kc) ? k + 1 : k;
            const int jn = nbr[(size_t)ci * KN + kn];
            const size_t pjn = (size_t)b * NP + jn;
            float yv_n = y[pjn * 64 + o];
            float jx_n = pos[pjn * 3], jy_n = pos[pjn * 3 + 1], jz_n = pos[pjn * 3 + 2];
            // ---- compute current message ----
            float rx = jx - cx, ry = jy - cy, rz = jz - cz;
            float h1 = fmaf(rx, wp0, yv);
            h1 = fmaf(ry, wp1, h1);
            h1 = fmaf(rz, wp2, h1);
            h1 = fmaxf(h1, 0.f);
            st1[o] = h1;
            float a2a = b2v, a2b = 0.f;
            #pragma unroll
            for (int fc = 0; fc < 16; fc += 2) {
                float4 hA = *(const float4*)&st1[fc * 4];
                float4 hB = *(const float4*)&st1[fc * 4 + 4];
                a2a = fmaf(hA.x, w2c[fc * 4], a2a);
                a2a = fmaf(hA.y, w2c[fc * 4 + 1], a2a);
                a2a = fmaf(hA.z, w2c[fc * 4 + 2], a2a);
                a2a = fmaf(hA.w, w2c[fc * 4 + 3], a2a);
                a2b = fmaf(hB.x, w2c[fc * 4 + 4], a2b);
                a2b = fmaf(hB.y, w2c[fc * 4 + 5], a2b);
                a2b = fmaf(hB.z, w2c[fc * 4 + 6], a2b);
                a2b = fmaf(hB.w, w2c[fc * 4 + 7], a2b);
            }
            float h2 = fmaxf(a2a + a2b, 0.f);
            st2[o] = h2;
            float a3 = b3av, a4 = b3bv;
            #pragma unroll
            for (int fc = 0; fc < 16; fc++) {
                float4 h = *(const float4*)&st2[fc * 4];
                a3 = fmaf(h.x, w3a[fc * 4], a3);
                a3 = fmaf(h.y, w3a[fc * 4 + 1], a3);
                a3 = fmaf(h.z, w3a[fc * 4 + 2], a3);
                a3 = fmaf(h.w, w3a[fc * 4 + 3], a3);
                a4 = fmaf(h.x, w3b[fc * 4], a4);
                a4 = fmaf(h.y, w3b[fc * 4 + 1], a4);
                a4 = fmaf(h.z, w3b[fc * 4 + 2], a4);
                a4 = fmaf(h.w, w3b[fc * 4 + 3], a4);
            }
            mA = fmaxf(mA, a3);
            mB = fmaxf(mB, a4);
            yv = yv_n; jx = jx_n; jy = jy_n; jz = jz_n;
        }
        out_x[(size_t)ci * 128 + o] = mA;
        out_x[(size_t)ci * 128 + 64 + o] = mB;
    }
}

extern "C" void kernel_launch(void* const* d_in, const int* in_sizes, int n_in,
                              void* d_out, int out_size, void* d_ws, size_t ws_size,
                              hipStream_t stream) {
    const float* x   = (const float*)d_in[0];
    const float* pos = (const float*)d_in[1];
    // d_in[2] = batch (int32) — layout is known (sorted, equal sized), unused
    const float* w1  = (const float*)d_in[3];
    const float* b1  = (const float*)d_in[4];
    const float* w2  = (const float*)d_in[5];
    const float* b2  = (const float*)d_in[6];
    const float* w3  = (const float*)d_in[7];
    const float* b3  = (const float*)d_in[8];

    float* out_x     = (float*)d_out;                       // [B*M,128]
    float* out_pos   = out_x + (size_t)BG * MC * 128;       // [B*M,3]
    float* out_batch = out_pos + (size_t)BG * MC * 3;       // [B*M] (written as float)

    char* ws   = (char*)d_ws;
    float* y   = (float*)ws;                    // 8 MB: [B*N,64] = x@W1x + b1
    int* cntg  = (int*)(ws + 8454144);          // 64 KB
    int* nbr   = (int*)(ws + 8519680);          // 4 MB

    hipLaunchKernelGGL(k1_fps_y, dim3(BG + 256), dim3(512), 0, stream,
                       pos, x, w1, b1, y, out_pos, out_batch);
    hipLaunchKernelGGL(k2_nbr, dim3(256), dim3(256), 0, stream,
                       pos, out_pos, nbr, cntg);
    hipLaunchKernelGGL(k3_mlp, dim3(4096), dim3(256), 0, stream,
                       y, pos, nbr, cntg, w1, w2, b2, w3, b3, out_pos, out_x);
}

// Round 7
// 1953.735 us; speedup vs baseline: 1.2022x; 1.2022x over previous
//
#include <hip/hip_runtime.h>

#define BG 8
#define NP 4096
#define MC 2048
#define KN 64

// Exact-rounding squared distance matching JAX/np f32 semantics.
__device__ __forceinline__ float dist2(float ax, float ay, float az,
                                       float bx, float by, float bz) {
    float dx = __fsub_rn(ax, bx), dy = __fsub_rn(ay, by), dz = __fsub_rn(az, bz);
    return __fadd_rn(__fadd_rn(__fmul_rn(dx, dx), __fmul_rn(dy, dy)), __fmul_rn(dz, dz));
}

template <int CTRL>
__device__ __forceinline__ float dppmax(float v) {
    int t = __builtin_amdgcn_update_dpp(0, __float_as_int(v), CTRL, 0xf, 0xf, true);
    return fmaxf(v, __int_as_float(t));
}
template <int CTRL>
__device__ __forceinline__ float dppmov(float v) {
    return __int_as_float(__builtin_amdgcn_update_dpp(0, __float_as_int(v), CTRL, 0xf, 0xf, true));
}

// ---- Kernel 1: FPS (blocks 0..7, 8 waves x 8 pts/thread) + y = x@W1x + b1 ----
__global__ __launch_bounds__(512) void k1_fps_y(
    const float* __restrict__ pos, const float* __restrict__ x,
    const float* __restrict__ w1, const float* __restrict__ b1,
    float* __restrict__ y,
    float* __restrict__ out_pos, float* __restrict__ out_batch)
{
    __shared__ float smem[12480];
    const int tid = threadIdx.x;
    if (blockIdx.x < BG) {
        const int b = blockIdx.x;
        const float* pg = pos + (size_t)b * NP * 3;
        for (int i = tid; i < NP * 3; i += 512) smem[i] = pg[i];
        __syncthreads();
        const int lane = tid & 63, wq = tid >> 6;   // 8 waves
        float px[8], py[8], pz[8], mind[8];
        const int base = tid * 8;
        #pragma unroll
        for (int i = 0; i < 8; i++) {
            px[i] = smem[(base + i) * 3];
            py[i] = smem[(base + i) * 3 + 1];
            pz[i] = smem[(base + i) * 3 + 2];
            mind[i] = 1e30f;
        }
        float4* slotA = (float4*)(smem + 12288);    // [2][8] : (V, x, y, z) double-buffered
        float cx = smem[0], cy = smem[1], cz = smem[2];
        // per-thread result buffer: this thread owns centers m = tid*4 + s
        float rx0, ry0, rz0, rx1, ry1, rz1, rx2, ry2, rz2, rx3, ry3, rz3;
        rx0 = cx; ry0 = cy; rz0 = cz;
        rx1 = ry1 = rz1 = 0.f; rx2 = ry2 = rz2 = 0.f; rx3 = ry3 = rz3 = 0.f;
        for (int m = 1; m < MC; m++) {
            // update min distances; track thread-local (max, first idx)
            float bv = -1.0f; int bi = base;
            #pragma unroll
            for (int i = 0; i < 8; i++) {
                float d = dist2(px[i], py[i], pz[i], cx, cy, cz);
                float nm = fminf(mind[i], d);
                mind[i] = nm;
                if (nm > bv) { bv = nm; bi = base + i; }  // strict > keeps first idx
            }
            // wave max via DPP
            float v = bv;
            v = dppmax<0x111>(v);  // row_shr:1
            v = dppmax<0x112>(v);  // row_shr:2
            v = dppmax<0x114>(v);  // row_shr:4
            v = dppmax<0x118>(v);  // row_shr:8
            v = dppmax<0x142>(v);  // row_bcast:15
            v = dppmax<0x143>(v);  // row_bcast:31
            const float V = __int_as_float(__builtin_amdgcn_readlane(__float_as_int(v), 63));
            // first candidate lane = min index (lane order == index order within wave)
            unsigned long long mk = __ballot(bv == V);
            const int db = (m & 1) * 8;
            if (lane == (int)(__ffsll((long long)mk) - 1)) {
                // ONLY the winner lane gathers its candidate's position (1 lane/wave)
                float wx = smem[bi * 3], wy = smem[bi * 3 + 1], wz = smem[bi * 3 + 2];
                slotA[db + wq] = make_float4(V, wx, wy, wz);
            }
            __syncthreads();
            // lane-parallel fold: ONE b128/thread (conflict-free: 8 addrs x 4 banks),
            // then 3 DPP tournament steps in registers. Position-based tie-break
            // (take-other iff oV>V, or oV==V and other is the lower wave) == first-index argmax.
            float4 s = slotA[db + (lane & 7)];
            {   // xor1: quad_perm [1,0,3,2]
                float4 o;
                o.x = dppmov<0xB1>(s.x); o.y = dppmov<0xB1>(s.y);
                o.z = dppmov<0xB1>(s.z); o.w = dppmov<0xB1>(s.w);
                bool take = (o.x > s.x) || ((lane & 1) && o.x == s.x);
                s.x = take ? o.x : s.x; s.y = take ? o.y : s.y;
                s.z = take ? o.z : s.z; s.w = take ? o.w : s.w;
            }
            {   // xor2: quad_perm [2,3,0,1]
                float4 o;
                o.x = dppmov<0x4E>(s.x); o.y = dppmov<0x4E>(s.y);
                o.z = dppmov<0x4E>(s.z); o.w = dppmov<0x4E>(s.w);
                bool take = (o.x > s.x) || ((lane & 2) && o.x == s.x);
                s.x = take ? o.x : s.x; s.y = take ? o.y : s.y;
                s.z = take ? o.z : s.z; s.w = take ? o.w : s.w;
            }
            {   // xor4: row_shl:4 (lanes g<4 see g+4), row_shr:4 (lanes g>=4 see g-4)
                const bool hi = (lane & 4) != 0;
                float oxl = dppmov<0x104>(s.x), oxr = dppmov<0x114>(s.x);
                float oyl = dppmov<0x104>(s.y), oyr = dppmov<0x114>(s.y);
                float ozl = dppmov<0x104>(s.z), ozr = dppmov<0x114>(s.z);
                float owl = dppmov<0x104>(s.w), owr = dppmov<0x114>(s.w);
                float ox = hi ? oxr : oxl, oy = hi ? oyr : oyl;
                float oz = hi ? ozr : ozl, ow = hi ? owr : owl;
                bool take = (ox > s.x) || (hi && ox == s.x);
                s.x = take ? ox : s.x; s.y = take ? oy : s.y;
                s.z = take ? oz : s.z; s.w = take ? ow : s.w;
            }
            cx = s.y; cy = s.z; cz = s.w;
            // buffer result in the owning thread's registers
            if ((m >> 2) == tid) {
                const int sel = m & 3;
                if      (sel == 0) { rx0 = cx; ry0 = cy; rz0 = cz; }
                else if (sel == 1) { rx1 = cx; ry1 = cy; rz1 = cz; }
                else if (sel == 2) { rx2 = cx; ry2 = cy; rz2 = cz; }
                else               { rx3 = cx; ry3 = cy; rz3 = cz; }
            }
        }
        // write out this thread's 4 centers
        const int c0 = b * MC + tid * 4;
        out_pos[(size_t)c0 * 3 + 0]  = rx0; out_pos[(size_t)c0 * 3 + 1]  = ry0; out_pos[(size_t)c0 * 3 + 2]  = rz0;
        out_pos[(size_t)c0 * 3 + 3]  = rx1; out_pos[(size_t)c0 * 3 + 4]  = ry1; out_pos[(size_t)c0 * 3 + 5]  = rz1;
        out_pos[(size_t)c0 * 3 + 6]  = rx2; out_pos[(size_t)c0 * 3 + 7]  = ry2; out_pos[(size_t)c0 * 3 + 8]  = rz2;
        out_pos[(size_t)c0 * 3 + 9]  = rx3; out_pos[(size_t)c0 * 3 + 10] = ry3; out_pos[(size_t)c0 * 3 + 11] = rz3;
        out_batch[c0 + 0] = (float)b; out_batch[c0 + 1] = (float)b;
        out_batch[c0 + 2] = (float)b; out_batch[c0 + 3] = (float)b;
    } else {
        // -------- y = x @ W1x + b1 (128 points per block) --------
        const int q = blockIdx.x - BG;   // 0..255
        const int p0 = q * 128;
        float* xs = smem;                 // 128 x 65 (padded)
        float* wsm = smem + 8320;         // 64 x 64
        float* bsm = smem + 12416;        // 64
        for (int i = tid; i < 8192; i += 512)
            xs[(i >> 6) * 65 + (i & 63)] = x[(size_t)p0 * 64 + i];
        for (int i = tid; i < 4096; i += 512) wsm[i] = w1[i];
        if (tid < 64) bsm[tid] = b1[tid];
        __syncthreads();
        const int pl = tid >> 2, oq = tid & 3;
        float acc[16];
        #pragma unroll
        for (int u = 0; u < 16; u++) acc[u] = bsm[oq * 16 + u];
        for (int f = 0; f < 64; f++) {
            float xv = xs[pl * 65 + f];
            const float4* wp = (const float4*)&wsm[f * 64 + oq * 16];
            float4 a = wp[0], b4 = wp[1], c4 = wp[2], d4 = wp[3];
            acc[0] = fmaf(xv, a.x, acc[0]);   acc[1] = fmaf(xv, a.y, acc[1]);
            acc[2] = fmaf(xv, a.z, acc[2]);   acc[3] = fmaf(xv, a.w, acc[3]);
            acc[4] = fmaf(xv, b4.x, acc[4]);  acc[5] = fmaf(xv, b4.y, acc[5]);
            acc[6] = fmaf(xv, b4.z, acc[6]);  acc[7] = fmaf(xv, b4.w, acc[7]);
            acc[8] = fmaf(xv, c4.x, acc[8]);  acc[9] = fmaf(xv, c4.y, acc[9]);
            acc[10] = fmaf(xv, c4.z, acc[10]); acc[11] = fmaf(xv, c4.w, acc[11]);
            acc[12] = fmaf(xv, d4.x, acc[12]); acc[13] = fmaf(xv, d4.y, acc[13]);
            acc[14] = fmaf(xv, d4.z, acc[14]); acc[15] = fmaf(xv, d4.w, acc[15]);
        }
        float4* yo = (float4*)&y[((size_t)p0 + pl) * 64 + oq * 16];
        yo[0] = make_float4(acc[0], acc[1], acc[2], acc[3]);
        yo[1] = make_float4(acc[4], acc[5], acc[6], acc[7]);
        yo[2] = make_float4(acc[8], acc[9], acc[10], acc[11]);
        yo[3] = make_float4(acc[12], acc[13], acc[14], acc[15]);
    }
}

// ---------------- Kernel 2: radius-capped kNN per center (centers from out_pos) -------------
__global__ __launch_bounds__(256) void k2_nbr(
    const float* __restrict__ pos, const float* __restrict__ out_pos,
    int* __restrict__ nbr, int* __restrict__ cntg)
{
    __shared__ float smem[12288 + 4 * 480 * 2];
    const int tid = threadIdx.x, lane = tid & 63, wv = tid >> 6;
    const int b = blockIdx.x >> 5, blk = blockIdx.x & 31;
    const float* pg = pos + (size_t)b * NP * 3;
    for (int i = tid; i < NP * 3; i += 256) smem[i] = pg[i];
    __syncthreads();
    float2* cb = (float2*)(smem + 12288) + wv * 480;
    const int wi = blk * 4 + wv;    // 0..127
    for (int t = 0; t < 16; t++) {
        const int m = wi + 128 * t, ci = b * MC + m;
        const float cx = out_pos[(size_t)ci * 3], cy = out_pos[(size_t)ci * 3 + 1], cz = out_pos[(size_t)ci * 3 + 2];
        int cnt = 0;
        for (int c = 0; c < 64; c++) {
            const int p = c * 64 + lane;
            float d2 = dist2(smem[p * 3], smem[p * 3 + 1], smem[p * 3 + 2], cx, cy, cz);
            bool inr = d2 <= 0.25f;
            unsigned long long mk = __ballot(inr);
            int pre = __popcll(mk & ((1ull << lane) - 1ull));
            int wp = cnt + pre;
            if (inr && wp < 480) cb[wp] = make_float2(d2, __int_as_float(p));
            cnt += __popcll(mk);
        }
        if (cnt > 480) cnt = 480;
        if (cnt <= KN) {
            if (lane < cnt) { float2 e = cb[lane]; nbr[(size_t)ci * KN + lane] = __float_as_int(e.y); }
            if (lane == 0) cntg[ci] = cnt;
        } else {
            for (int basej = 0; basej < cnt; basej += 64) {
                int jj = basej + lane;
                float dj = 3.4e38f; int ij = 0x7fffffff;
                bool act = jj < cnt;
                if (act) { float2 e = cb[jj]; dj = e.x; ij = __float_as_int(e.y); }
                int rank = 0;
                for (int l = 0; l < cnt; l++) {
                    float2 e = cb[l];
                    float dl = e.x; int il = __float_as_int(e.y);
                    if (dl < dj || (dl == dj && il < ij)) rank++;
                }
                if (act && rank < KN) nbr[(size_t)ci * KN + rank] = ij;
            }
            if (lane == 0) cntg[ci] = KN;
        }
    }
}

// ------- Kernel 3: per-center MLP + masked max (1 center/wave, prefetch pipeline) -------
__global__ __launch_bounds__(256, 2) void k3_mlp(
    const float* __restrict__ y, const float* __restrict__ pos,
    const int* __restrict__ nbr, const int* __restrict__ cntg,
    const float* __restrict__ w1, const float* __restrict__ w2, const float* __restrict__ b2,
    const float* __restrict__ w3, const float* __restrict__ b3,
    const float* __restrict__ out_pos, float* __restrict__ out_x)
{
    __shared__ float smem[4 * 136];
    const int tid = threadIdx.x, o = tid & 63, wv = tid >> 6;
    float w2c[64], w3a[64], w3b[64];
    #pragma unroll
    for (int f = 0; f < 64; f++) {
        w2c[f] = w2[f * 64 + o];
        w3a[f] = w3[f * 128 + o];
        w3b[f] = w3[f * 128 + 64 + o];
    }
    const float b2v = b2[o], b3av = b3[o], b3bv = b3[o + 64];
    const float wp0 = w1[64 * 64 + o], wp1 = w1[65 * 64 + o], wp2 = w1[66 * 64 + o];
    float* st1 = smem + wv * 136;
    float* st2 = st1 + 68;
    const int ci = blockIdx.x * 4 + wv;   // 0..16383
    const int b = ci >> 11;               // / MC
    const int kc = cntg[ci];
    const float cx = out_pos[(size_t)ci * 3], cy = out_pos[(size_t)ci * 3 + 1], cz = out_pos[(size_t)ci * 3 + 2];
    {
        const int j0 = nbr[(size_t)ci * KN];
        const size_t pj0 = (size_t)b * NP + j0;
        float yv = y[pj0 * 64 + o];
        float jx = pos[pj0 * 3], jy = pos[pj0 * 3 + 1], jz = pos[pj0 * 3 + 2];
        float mA = -3.4e38f, mB = -3.4e38f;
        for (int k = 0; k < kc; k++) {
            const int kn = (k + 1 < kc) ? k + 1 : k;
            const int jn = nbr[(size_t)ci * KN + kn];
            const size_t pjn = (size_t)b * NP + jn;
            float yv_n = y[pjn * 64 + o];
            float jx_n = pos[pjn * 3], jy_n = pos[pjn * 3 + 1], jz_n = pos[pjn * 3 + 2];
            // ---- compute current message ----
            float rx = jx - cx, ry = jy - cy, rz = jz - cz;
            float h1 = fmaf(rx, wp0, yv);
            h1 = fmaf(ry, wp1, h1);
            h1 = fmaf(rz, wp2, h1);
            h1 = fmaxf(h1, 0.f);
            st1[o] = h1;
            float a2a = b2v, a2b = 0.f;
            #pragma unroll
            for (int fc = 0; fc < 16; fc += 2) {
                float4 hA = *(const float4*)&st1[fc * 4];
                float4 hB = *(const float4*)&st1[fc * 4 + 4];
                a2a = fmaf(hA.x, w2c[fc * 4], a2a);
                a2a = fmaf(hA.y, w2c[fc * 4 + 1], a2a);
                a2a = fmaf(hA.z, w2c[fc * 4 + 2], a2a);
                a2a = fmaf(hA.w, w2c[fc * 4 + 3], a2a);
                a2b = fmaf(hB.x, w2c[fc * 4 + 4], a2b);
                a2b = fmaf(hB.y, w2c[fc * 4 + 5], a2b);
                a2b = fmaf(hB.z, w2c[fc * 4 + 6], a2b);
                a2b = fmaf(hB.w, w2c[fc * 4 + 7], a2b);
            }
            float h2 = fmaxf(a2a + a2b, 0.f);
            st2[o] = h2;
            float a3 = b3av, a4 = b3bv;
            #pragma unroll
            for (int fc = 0; fc < 16; fc++) {
                float4 h = *(const float4*)&st2[fc * 4];
                a3 = fmaf(h.x, w3a[fc * 4], a3);
                a3 = fmaf(h.y, w3a[fc * 4 + 1], a3);
                a3 = fmaf(h.z, w3a[fc * 4 + 2], a3);
                a3 = fmaf(h.w, w3a[fc * 4 + 3], a3);
                a4 = fmaf(h.x, w3b[fc * 4], a4);
                a4 = fmaf(h.y, w3b[fc * 4 + 1], a4);
                a4 = fmaf(h.z, w3b[fc * 4 + 2], a4);
                a4 = fmaf(h.w, w3b[fc * 4 + 3], a4);
            }
            mA = fmaxf(mA, a3);
            mB = fmaxf(mB, a4);
            yv = yv_n; jx = jx_n; jy = jy_n; jz = jz_n;
        }
        out_x[(size_t)ci * 128 + o] = mA;
        out_x[(size_t)ci * 128 + 64 + o] = mB;
    }
}

extern "C" void kernel_launch(void* const* d_in, const int* in_sizes, int n_in,
                              void* d_out, int out_size, void* d_ws, size_t ws_size,
                              hipStream_t stream) {
    const float* x   = (const float*)d_in[0];
    const float* pos = (const float*)d_in[1];
    const float* w1  = (const float*)d_in[3];
    const float* b1  = (const float*)d_in[4];
    const float* w2  = (const float*)d_in[5];
    const float* b2  = (const float*)d_in[6];
    const float* w3  = (const float*)d_in[7];
    const float* b3  = (const float*)d_in[8];

    float* out_x     = (float*)d_out;                       // [B*M,128]
    float* out_pos   = out_x + (size_t)BG * MC * 128;       // [B*M,3]
    float* out_batch = out_pos + (size_t)BG * MC * 3;       // [B*M] (written as float)

    char* ws   = (char*)d_ws;
    float* y   = (float*)ws;                    // 8 MB: [B*N,64] = x@W1x + b1
    int* cntg  = (int*)(ws + 8454144);          // 64 KB
    int* nbr   = (int*)(ws + 8519680);          // 4 MB

    hipLaunchKernelGGL(k1_fps_y, dim3(BG + 256), dim3(512), 0, stream,
                       pos, x, w1, b1, y, out_pos, out_batch);
    hipLaunchKernelGGL(k2_nbr, dim3(256), dim3(256), 0, stream,
                       pos, out_pos, nbr, cntg);
    hipLaunchKernelGGL(k3_mlp, dim3(4096), dim3(256), 0, stream,
                       y, pos, nbr, cntg, w1, w2, b2, w3, b3, out_pos, out_x);
}

// Round 8
// 1943.924 us; speedup vs baseline: 1.2083x; 1.0050x over previous
//
#include <hip/hip_runtime.h>

#define BG 8
#define NP 4096
#define MC 2048
#define KN 64

// Exact-rounding squared distance matching JAX/np f32 semantics.
__device__ __forceinline__ float dist2(float ax, float ay, float az,
                                       float bx, float by, float bz) {
    float dx = __fsub_rn(ax, bx), dy = __fsub_rn(ay, by), dz = __fsub_rn(az, bz);
    return __fadd_rn(__fadd_rn(__fmul_rn(dx, dx), __fmul_rn(dy, dy)), __fmul_rn(dz, dz));
}

template <int CTRL>
__device__ __forceinline__ float dppmax(float v) {
    int t = __builtin_amdgcn_update_dpp(0, __float_as_int(v), CTRL, 0xf, 0xf, true);
    return fmaxf(v, __int_as_float(t));
}
template <int CTRL>
__device__ __forceinline__ float dppmov(float v) {
    return __int_as_float(__builtin_amdgcn_update_dpp(0, __float_as_int(v), CTRL, 0xf, 0xf, true));
}

// ---- Kernel 1: FPS (blocks 0..7, 8 waves x 8 pts/thread) + y = x@W1x + b1 ----
// launch_bounds(512, 1): 8-wave block => 2 waves/SIMD => VGPR cap 256, so the
// per-thread point arrays (px/py/pz/mind = 32 regs) stay register-resident.
__global__ __launch_bounds__(512, 1) void k1_fps_y(
    const float* __restrict__ pos, const float* __restrict__ x,
    const float* __restrict__ w1, const float* __restrict__ b1,
    float* __restrict__ y,
    float* __restrict__ out_pos, float* __restrict__ out_batch)
{
    __shared__ float smem[12480];
    const int tid = threadIdx.x;
    if (blockIdx.x < BG) {
        const int b = blockIdx.x;
        const float* pg = pos + (size_t)b * NP * 3;
        for (int i = tid; i < NP * 3; i += 512) smem[i] = pg[i];
        __syncthreads();
        const int lane = tid & 63, wq = tid >> 6;   // 8 waves
        float px[8], py[8], pz[8], mind[8];
        const int base = tid * 8;
        #pragma unroll
        for (int i = 0; i < 8; i++) {
            px[i] = smem[(base + i) * 3];
            py[i] = smem[(base + i) * 3 + 1];
            pz[i] = smem[(base + i) * 3 + 2];
            mind[i] = 1e30f;
        }
        float4* slotA = (float4*)(smem + 12288);    // [2][8] : (V, x, y, z) double-buffered
        float cx = smem[0], cy = smem[1], cz = smem[2];
        // per-thread result buffer: this thread owns centers m = tid*4 + s
        float rx0, ry0, rz0, rx1, ry1, rz1, rx2, ry2, rz2, rx3, ry3, rz3;
        rx0 = cx; ry0 = cy; rz0 = cz;
        rx1 = ry1 = rz1 = 0.f; rx2 = ry2 = rz2 = 0.f; rx3 = ry3 = rz3 = 0.f;
        for (int m = 1; m < MC; m++) {
            // update min distances; track thread-local (max, first idx)
            float bv = -1.0f; int bi = base;
            #pragma unroll
            for (int i = 0; i < 8; i++) {
                float d = dist2(px[i], py[i], pz[i], cx, cy, cz);
                float nm = fminf(mind[i], d);
                mind[i] = nm;
                if (nm > bv) { bv = nm; bi = base + i; }  // strict > keeps first idx
            }
            // wave max via DPP
            float v = bv;
            v = dppmax<0x111>(v);  // row_shr:1
            v = dppmax<0x112>(v);  // row_shr:2
            v = dppmax<0x114>(v);  // row_shr:4
            v = dppmax<0x118>(v);  // row_shr:8
            v = dppmax<0x142>(v);  // row_bcast:15
            v = dppmax<0x143>(v);  // row_bcast:31
            const float V = __int_as_float(__builtin_amdgcn_readlane(__float_as_int(v), 63));
            // first candidate lane = min index (lane order == index order within wave)
            unsigned long long mk = __ballot(bv == V);
            const int db = (m & 1) * 8;
            if (lane == (int)(__ffsll((long long)mk) - 1)) {
                // ONLY the winner lane gathers its candidate's position (1 lane/wave)
                float wx = smem[bi * 3], wy = smem[bi * 3 + 1], wz = smem[bi * 3 + 2];
                slotA[db + wq] = make_float4(V, wx, wy, wz);
            }
            __syncthreads();
            // lane-parallel fold: ONE b128/thread (conflict-free: 8 addrs x 4 banks),
            // then 3 DPP tournament steps in registers. Position-based tie-break
            // (take-other iff oV>V, or oV==V and other is the lower wave) == first-index argmax.
            float4 s = slotA[db + (lane & 7)];
            {   // xor1: quad_perm [1,0,3,2]
                float4 o;
                o.x = dppmov<0xB1>(s.x); o.y = dppmov<0xB1>(s.y);
                o.z = dppmov<0xB1>(s.z); o.w = dppmov<0xB1>(s.w);
                bool take = (o.x > s.x) || ((lane & 1) && o.x == s.x);
                s.x = take ? o.x : s.x; s.y = take ? o.y : s.y;
                s.z = take ? o.z : s.z; s.w = take ? o.w : s.w;
            }
            {   // xor2: quad_perm [2,3,0,1]
                float4 o;
                o.x = dppmov<0x4E>(s.x); o.y = dppmov<0x4E>(s.y);
                o.z = dppmov<0x4E>(s.z); o.w = dppmov<0x4E>(s.w);
                bool take = (o.x > s.x) || ((lane & 2) && o.x == s.x);
                s.x = take ? o.x : s.x; s.y = take ? o.y : s.y;
                s.z = take ? o.z : s.z; s.w = take ? o.w : s.w;
            }
            {   // xor4: row_shl:4 (lanes g<4 see g+4), row_shr:4 (lanes g>=4 see g-4)
                const bool hi = (lane & 4) != 0;
                float oxl = dppmov<0x104>(s.x), oxr = dppmov<0x114>(s.x);
                float oyl = dppmov<0x104>(s.y), oyr = dppmov<0x114>(s.y);
                float ozl = dppmov<0x104>(s.z), ozr = dppmov<0x114>(s.z);
                float owl = dppmov<0x104>(s.w), owr = dppmov<0x114>(s.w);
                float ox = hi ? oxr : oxl, oy = hi ? oyr : oyl;
                float oz = hi ? ozr : ozl, ow = hi ? owr : owl;
                bool take = (ox > s.x) || (hi && ox == s.x);
                s.x = take ? ox : s.x; s.y = take ? oy : s.y;
                s.z = take ? oz : s.z; s.w = take ? ow : s.w;
            }
            cx = s.y; cy = s.z; cz = s.w;
            // buffer result in the owning thread's registers
            if ((m >> 2) == tid) {
                const int sel = m & 3;
                if      (sel == 0) { rx0 = cx; ry0 = cy; rz0 = cz; }
                else if (sel == 1) { rx1 = cx; ry1 = cy; rz1 = cz; }
                else if (sel == 2) { rx2 = cx; ry2 = cy; rz2 = cz; }
                else               { rx3 = cx; ry3 = cy; rz3 = cz; }
            }
        }
        // write out this thread's 4 centers
        const int c0 = b * MC + tid * 4;
        out_pos[(size_t)c0 * 3 + 0]  = rx0; out_pos[(size_t)c0 * 3 + 1]  = ry0; out_pos[(size_t)c0 * 3 + 2]  = rz0;
        out_pos[(size_t)c0 * 3 + 3]  = rx1; out_pos[(size_t)c0 * 3 + 4]  = ry1; out_pos[(size_t)c0 * 3 + 5]  = rz1;
        out_pos[(size_t)c0 * 3 + 6]  = rx2; out_pos[(size_t)c0 * 3 + 7]  = ry2; out_pos[(size_t)c0 * 3 + 8]  = rz2;
        out_pos[(size_t)c0 * 3 + 9]  = rx3; out_pos[(size_t)c0 * 3 + 10] = ry3; out_pos[(size_t)c0 * 3 + 11] = rz3;
        out_batch[c0 + 0] = (float)b; out_batch[c0 + 1] = (float)b;
        out_batch[c0 + 2] = (float)b; out_batch[c0 + 3] = (float)b;
    } else {
        // -------- y = x @ W1x + b1 (128 points per block) --------
        const int q = blockIdx.x - BG;   // 0..255
        const int p0 = q * 128;
        float* xs = smem;                 // 128 x 65 (padded)
        float* wsm = smem + 8320;         // 64 x 64
        float* bsm = smem + 12416;        // 64
        for (int i = tid; i < 8192; i += 512)
            xs[(i >> 6) * 65 + (i & 63)] = x[(size_t)p0 * 64 + i];
        for (int i = tid; i < 4096; i += 512) wsm[i] = w1[i];
        if (tid < 64) bsm[tid] = b1[tid];
        __syncthreads();
        const int pl = tid >> 2, oq = tid & 3;
        float acc[16];
        #pragma unroll
        for (int u = 0; u < 16; u++) acc[u] = bsm[oq * 16 + u];
        for (int f = 0; f < 64; f++) {
            float xv = xs[pl * 65 + f];
            const float4* wp = (const float4*)&wsm[f * 64 + oq * 16];
            float4 a = wp[0], b4 = wp[1], c4 = wp[2], d4 = wp[3];
            acc[0] = fmaf(xv, a.x, acc[0]);   acc[1] = fmaf(xv, a.y, acc[1]);
            acc[2] = fmaf(xv, a.z, acc[2]);   acc[3] = fmaf(xv, a.w, acc[3]);
            acc[4] = fmaf(xv, b4.x, acc[4]);  acc[5] = fmaf(xv, b4.y, acc[5]);
            acc[6] = fmaf(xv, b4.z, acc[6]);  acc[7] = fmaf(xv, b4.w, acc[7]);
            acc[8] = fmaf(xv, c4.x, acc[8]);  acc[9] = fmaf(xv, c4.y, acc[9]);
            acc[10] = fmaf(xv, c4.z, acc[10]); acc[11] = fmaf(xv, c4.w, acc[11]);
            acc[12] = fmaf(xv, d4.x, acc[12]); acc[13] = fmaf(xv, d4.y, acc[13]);
            acc[14] = fmaf(xv, d4.z, acc[14]); acc[15] = fmaf(xv, d4.w, acc[15]);
        }
        float4* yo = (float4*)&y[((size_t)p0 + pl) * 64 + oq * 16];
        yo[0] = make_float4(acc[0], acc[1], acc[2], acc[3]);
        yo[1] = make_float4(acc[4], acc[5], acc[6], acc[7]);
        yo[2] = make_float4(acc[8], acc[9], acc[10], acc[11]);
        yo[3] = make_float4(acc[12], acc[13], acc[14], acc[15]);
    }
}

// ---------------- Kernel 2: radius-capped kNN per center (centers from out_pos) -------------
__global__ __launch_bounds__(256) void k2_nbr(
    const float* __restrict__ pos, const float* __restrict__ out_pos,
    int* __restrict__ nbr, int* __restrict__ cntg)
{
    __shared__ float smem[12288 + 4 * 480 * 2];
    const int tid = threadIdx.x, lane = tid & 63, wv = tid >> 6;
    const int b = blockIdx.x >> 5, blk = blockIdx.x & 31;
    const float* pg = pos + (size_t)b * NP * 3;
    for (int i = tid; i < NP * 3; i += 256) smem[i] = pg[i];
    __syncthreads();
    float2* cb = (float2*)(smem + 12288) + wv * 480;
    const int wi = blk * 4 + wv;    // 0..127
    for (int t = 0; t < 16; t++) {
        const int m = wi + 128 * t, ci = b * MC + m;
        const float cx = out_pos[(size_t)ci * 3], cy = out_pos[(size_t)ci * 3 + 1], cz = out_pos[(size_t)ci * 3 + 2];
        int cnt = 0;
        for (int c = 0; c < 64; c++) {
            const int p = c * 64 + lane;
            float d2 = dist2(smem[p * 3], smem[p * 3 + 1], smem[p * 3 + 2], cx, cy, cz);
            bool inr = d2 <= 0.25f;
            unsigned long long mk = __ballot(inr);
            int pre = __popcll(mk & ((1ull << lane) - 1ull));
            int wp = cnt + pre;
            if (inr && wp < 480) cb[wp] = make_float2(d2, __int_as_float(p));
            cnt += __popcll(mk);
        }
        if (cnt > 480) cnt = 480;
        if (cnt <= KN) {
            if (lane < cnt) { float2 e = cb[lane]; nbr[(size_t)ci * KN + lane] = __float_as_int(e.y); }
            if (lane == 0) cntg[ci] = cnt;
        } else {
            for (int basej = 0; basej < cnt; basej += 64) {
                int jj = basej + lane;
                float dj = 3.4e38f; int ij = 0x7fffffff;
                bool act = jj < cnt;
                if (act) { float2 e = cb[jj]; dj = e.x; ij = __float_as_int(e.y); }
                int rank = 0;
                for (int l = 0; l < cnt; l++) {
                    float2 e = cb[l];
                    float dl = e.x; int il = __float_as_int(e.y);
                    if (dl < dj || (dl == dj && il < ij)) rank++;
                }
                if (act && rank < KN) nbr[(size_t)ci * KN + rank] = ij;
            }
            if (lane == 0) cntg[ci] = KN;
        }
    }
}

// ------- Kernel 3: per-center MLP + masked max (1 center/wave, prefetch pipeline) -------
// launch_bounds(256, 1): the 192 weight values/thread must be register-resident
// (VGPR ~220 < 256); the old (256,2) cap of 128 VGPR spilled them to scratch.
__global__ __launch_bounds__(256, 1) void k3_mlp(
    const float* __restrict__ y, const float* __restrict__ pos,
    const int* __restrict__ nbr, const int* __restrict__ cntg,
    const float* __restrict__ w1, const float* __restrict__ w2, const float* __restrict__ b2,
    const float* __restrict__ w3, const float* __restrict__ b3,
    const float* __restrict__ out_pos, float* __restrict__ out_x)
{
    __shared__ float smem[4 * 136];
    const int tid = threadIdx.x, o = tid & 63, wv = tid >> 6;
    float w2c[64], w3a[64], w3b[64];
    #pragma unroll
    for (int f = 0; f < 64; f++) {
        w2c[f] = w2[f * 64 + o];
        w3a[f] = w3[f * 128 + o];
        w3b[f] = w3[f * 128 + 64 + o];
    }
    const float b2v = b2[o], b3av = b3[o], b3bv = b3[o + 64];
    const float wp0 = w1[64 * 64 + o], wp1 = w1[65 * 64 + o], wp2 = w1[66 * 64 + o];
    float* st1 = smem + wv * 136;
    float* st2 = st1 + 68;
    const int ci = blockIdx.x * 4 + wv;   // 0..16383
    const int b = ci >> 11;               // / MC
    const int kc = cntg[ci];
    const float cx = out_pos[(size_t)ci * 3], cy = out_pos[(size_t)ci * 3 + 1], cz = out_pos[(size_t)ci * 3 + 2];
    {
        const int j0 = nbr[(size_t)ci * KN];
        const size_t pj0 = (size_t)b * NP + j0;
        float yv = y[pj0 * 64 + o];
        float jx = pos[pj0 * 3], jy = pos[pj0 * 3 + 1], jz = pos[pj0 * 3 + 2];
        float mA = -3.4e38f, mB = -3.4e38f;
        for (int k = 0; k < kc; k++) {
            const int kn = (k + 1 < kc) ? k + 1 : k;
            const int jn = nbr[(size_t)ci * KN + kn];
            const size_t pjn = (size_t)b * NP + jn;
            float yv_n = y[pjn * 64 + o];
            float jx_n = pos[pjn * 3], jy_n = pos[pjn * 3 + 1], jz_n = pos[pjn * 3 + 2];
            // ---- compute current message ----
            float rx = jx - cx, ry = jy - cy, rz = jz - cz;
            float h1 = fmaf(rx, wp0, yv);
            h1 = fmaf(ry, wp1, h1);
            h1 = fmaf(rz, wp2, h1);
            h1 = fmaxf(h1, 0.f);
            st1[o] = h1;
            float a2a = b2v, a2b = 0.f;
            #pragma unroll
            for (int fc = 0; fc < 16; fc += 2) {
                float4 hA = *(const float4*)&st1[fc * 4];
                float4 hB = *(const float4*)&st1[fc * 4 + 4];
                a2a = fmaf(hA.x, w2c[fc * 4], a2a);
                a2a = fmaf(hA.y, w2c[fc * 4 + 1], a2a);
                a2a = fmaf(hA.z, w2c[fc * 4 + 2], a2a);
                a2a = fmaf(hA.w, w2c[fc * 4 + 3], a2a);
                a2b = fmaf(hB.x, w2c[fc * 4 + 4], a2b);
                a2b = fmaf(hB.y, w2c[fc * 4 + 5], a2b);
                a2b = fmaf(hB.z, w2c[fc * 4 + 6], a2b);
                a2b = fmaf(hB.w, w2c[fc * 4 + 7], a2b);
            }
            float h2 = fmaxf(a2a + a2b, 0.f);
            st2[o] = h2;
            float a3 = b3av, a4 = b3bv;
            #pragma unroll
            for (int fc = 0; fc < 16; fc++) {
                float4 h = *(const float4*)&st2[fc * 4];
                a3 = fmaf(h.x, w3a[fc * 4], a3);
                a3 = fmaf(h.y, w3a[fc * 4 + 1], a3);
                a3 = fmaf(h.z, w3a[fc * 4 + 2], a3);
                a3 = fmaf(h.w, w3a[fc * 4 + 3], a3);
                a4 = fmaf(h.x, w3b[fc * 4], a4);
                a4 = fmaf(h.y, w3b[fc * 4 + 1], a4);
                a4 = fmaf(h.z, w3b[fc * 4 + 2], a4);
                a4 = fmaf(h.w, w3b[fc * 4 + 3], a4);
            }
            mA = fmaxf(mA, a3);
            mB = fmaxf(mB, a4);
            yv = yv_n; jx = jx_n; jy = jy_n; jz = jz_n;
        }
        out_x[(size_t)ci * 128 + o] = mA;
        out_x[(size_t)ci * 128 + 64 + o] = mB;
    }
}

extern "C" void kernel_launch(void* const* d_in, const int* in_sizes, int n_in,
                              void* d_out, int out_size, void* d_ws, size_t ws_size,
                              hipStream_t stream) {
    const float* x   = (const float*)d_in[0];
    const float* pos = (const float*)d_in[1];
    const float* w1  = (const float*)d_in[3];
    const float* b1  = (const float*)d_in[4];
    const float* w2  = (const float*)d_in[5];
    const float* b2  = (const float*)d_in[6];
    const float* w3  = (const float*)d_in[7];
    const float* b3  = (const float*)d_in[8];

    float* out_x     = (float*)d_out;                       // [B*M,128]
    float* out_pos   = out_x + (size_t)BG * MC * 128;       // [B*M,3]
    float* out_batch = out_pos + (size_t)BG * MC * 3;       // [B*M] (written as float)

    char* ws   = (char*)d_ws;
    float* y   = (float*)ws;                    // 8 MB: [B*N,64] = x@W1x + b1
    int* cntg  = (int*)(ws + 8454144);          // 64 KB
    int* nbr   = (int*)(ws + 8519680);          // 4 MB

    hipLaunchKernelGGL(k1_fps_y, dim3(BG + 256), dim3(512), 0, stream,
                       pos, x, w1, b1, y, out_pos, out_batch);
    hipLaunchKernelGGL(k2_nbr, dim3(256), dim3(256), 0, stream,
                       pos, out_pos, nbr, cntg);
    hipLaunchKernelGGL(k3_mlp, dim3(4096), dim3(256), 0, stream,
                       y, pos, nbr, cntg, w1, w2, b2, w3, b3, out_pos, out_x);
}